// Round 1
// baseline (1394.507 us; speedup 1.0000x reference)
//
#include <hip/hip_runtime.h>

// SmallSNN: T=50, B=128, ni=16384, nh=256, no=11
// Pipeline: gemm1 (time-batched, split-K=4, fp32 vector FMA)
//        -> reduce (sum split-K partials + b1)
//        -> scan1  (per-(b,h) membrane recursion, writes spk1)
//        -> gemm2  (spk1 @ W2.T + b2, wave-per-row)
//        -> scan2  (per-(b,o) membrane recursion, writes spk2 = output)

#define T_STEPS 50
#define BATCH   128
#define NI      16384
#define NH      256
#define NO      11
#define M_TOT   (T_STEPS * BATCH)   // 6400 rows
#define KSPLIT  4
#define KCHUNK  (NI / KSPLIT)       // 4096

// GEMM1 tiling
#define BM 64
#define BN 64
#define BK 64
#define LSTR 68                     // BM + 4 pad (keeps 16B alignment for b128 reads)

__global__ __launch_bounds__(256) void gemm1_kernel(
    const float* __restrict__ X, const float* __restrict__ W1,
    float* __restrict__ part)
{
    __shared__ float As[BK][LSTR];   // k-outer (transposed on store)
    __shared__ float Bs[BK][LSTR];

    const int mt = blockIdx.x;       // 0..99
    const int nt = blockIdx.y;       // 0..3
    const int ks = blockIdx.z;       // 0..3 (split-K)
    const int m0 = mt * BM, n0 = nt * BN;
    const int tid = threadIdx.x;
    const int tx = tid & 15;         // n-dir thread coord
    const int ty = tid >> 4;         // m-dir thread coord
    const int lr = tid >> 4;         // staging row base (0..15)
    const int lc = (tid & 15) << 2;  // staging k offset (0..60)

    const float* Abase = X  + (size_t)m0 * NI + (size_t)ks * KCHUNK;
    const float* Bbase = W1 + (size_t)n0 * NI + (size_t)ks * KCHUNK;

    float acct[4][4];   // total accumulator
    float accl[4][4];   // per-K-tile local accumulator (two-level sum for accuracy)
#pragma unroll
    for (int i = 0; i < 4; ++i)
#pragma unroll
        for (int j = 0; j < 4; ++j) { acct[i][j] = 0.f; accl[i][j] = 0.f; }

    for (int kt = 0; kt < KCHUNK / BK; ++kt) {
        const int k0 = kt * BK;
        // ---- stage A/B tiles (coalesced float4 global, transposed b32 LDS writes)
#pragma unroll
        for (int i = 0; i < 4; ++i) {
            const int row = lr + 16 * i;
            const float4 av = *(const float4*)(Abase + (size_t)row * NI + (k0 + lc));
            const float4 bv = *(const float4*)(Bbase + (size_t)row * NI + (k0 + lc));
            As[lc + 0][row] = av.x; As[lc + 1][row] = av.y;
            As[lc + 2][row] = av.z; As[lc + 3][row] = av.w;
            Bs[lc + 0][row] = bv.x; Bs[lc + 1][row] = bv.y;
            Bs[lc + 2][row] = bv.z; Bs[lc + 3][row] = bv.w;
        }
        __syncthreads();

        // ---- inner product: 2x ds_read_b128 + 16 FMA per kk
#pragma unroll 8
        for (int kk = 0; kk < BK; ++kk) {
            const float4 a = *(const float4*)&As[kk][ty << 2];
            const float4 b = *(const float4*)&Bs[kk][tx << 2];
            const float aa[4] = { a.x, a.y, a.z, a.w };
            const float bb[4] = { b.x, b.y, b.z, b.w };
#pragma unroll
            for (int i = 0; i < 4; ++i)
#pragma unroll
                for (int j = 0; j < 4; ++j)
                    accl[i][j] += aa[i] * bb[j];
        }
        // flush local into total (blocked summation: BLAS-class accuracy)
#pragma unroll
        for (int i = 0; i < 4; ++i)
#pragma unroll
            for (int j = 0; j < 4; ++j) { acct[i][j] += accl[i][j]; accl[i][j] = 0.f; }
        __syncthreads();
    }

    float* P = part + (size_t)ks * M_TOT * NH;
#pragma unroll
    for (int i = 0; i < 4; ++i) {
        const int m = m0 + (ty << 2) + i;
        float4 v;
        v.x = acct[i][0]; v.y = acct[i][1]; v.z = acct[i][2]; v.w = acct[i][3];
        *(float4*)(P + (size_t)m * NH + n0 + (tx << 2)) = v;
    }
}

// sum split-K partials + bias -> cur1  (deterministic, no atomics)
__global__ __launch_bounds__(256) void reduce_kernel(
    const float* __restrict__ part, const float* __restrict__ b1,
    float* __restrict__ cur1)
{
    const size_t gid = (size_t)blockIdx.x * 256 + threadIdx.x;  // over float4s
    const size_t off = gid * 4;                                  // element offset
    const size_t stride = (size_t)M_TOT * NH;
    float4 s0 = *(const float4*)(part + off);
    float4 s1 = *(const float4*)(part + stride + off);
    float4 s2 = *(const float4*)(part + 2 * stride + off);
    float4 s3 = *(const float4*)(part + 3 * stride + off);
    const int n = (int)(off & (NH - 1));
    const float4 bb = *(const float4*)(b1 + n);
    float4 r;
    r.x = (s0.x + s1.x) + (s2.x + s3.x) + bb.x;
    r.y = (s0.y + s1.y) + (s2.y + s3.y) + bb.y;
    r.z = (s0.z + s1.z) + (s2.z + s3.z) + bb.z;
    r.w = (s0.w + s1.w) + (s2.w + s3.w) + bb.w;
    *(float4*)(cur1 + off) = r;
}

// per-(b,h) layer-1 membrane recursion; emits spk1
__global__ __launch_bounds__(256) void scan1_kernel(
    const float* __restrict__ cur1, float* __restrict__ spk1)
{
    const int b = blockIdx.x;    // 0..127
    const int h = threadIdx.x;   // 0..255
    float mem = 0.f;
    for (int t = 0; t < T_STEPS; ++t) {
        const size_t idx = ((size_t)(t * BATCH + b)) * NH + h;
        const float c = cur1[idx];
        mem = __fadd_rn(__fmul_rn(0.9f, mem), c);   // two roundings, match numpy
        const float s = (mem > 1.0f) ? 1.0f : 0.0f;
        mem -= s;                                    // subtract-reset (exact)
        spk1[idx] = s;
    }
}

// cur2 = spk1 @ W2.T + b2 ; wave-per-row, shfl-xor tree reduction (K=256)
__global__ __launch_bounds__(256) void gemm2_kernel(
    const float* __restrict__ spk1, const float* __restrict__ W2,
    const float* __restrict__ b2, float* __restrict__ cur2)
{
    const int wave = threadIdx.x >> 6;
    const int lane = threadIdx.x & 63;
    const int m = blockIdx.x * 4 + wave;   // 0..6399
    const float4 s4 = *(const float4*)(spk1 + (size_t)m * NH + (lane << 2));
#pragma unroll
    for (int o = 0; o < NO; ++o) {
        const float4 w4 = *(const float4*)(W2 + (size_t)o * NH + (lane << 2));
        float p = (s4.x * w4.x + s4.y * w4.y) + (s4.z * w4.z + s4.w * w4.w);
#pragma unroll
        for (int d = 32; d; d >>= 1) p += __shfl_xor(p, d, 64);
        if (lane == 0) cur2[(size_t)m * 16 + o] = p + b2[o];
    }
}

// per-(b,o) layer-2 membrane recursion; emits spk2 = final output
__global__ __launch_bounds__(256) void scan2_kernel(
    const float* __restrict__ cur2, float* __restrict__ out)
{
    const int tid = blockIdx.x * 256 + threadIdx.x;
    if (tid >= BATCH * NO) return;
    const int b = tid / NO, o = tid % NO;
    float mem = 0.f;
    for (int t = 0; t < T_STEPS; ++t) {
        const float c = cur2[(size_t)(t * BATCH + b) * 16 + o];
        mem = __fadd_rn(__fmul_rn(0.9f, mem), c);
        const float s = (mem > 1.0f) ? 1.0f : 0.0f;
        mem -= s;
        out[(size_t)(t * BATCH + b) * NO + o] = s;
    }
}

extern "C" void kernel_launch(void* const* d_in, const int* in_sizes, int n_in,
                              void* d_out, int out_size, void* d_ws, size_t ws_size,
                              hipStream_t stream) {
    const float* x  = (const float*)d_in[0];   // [50,128,128,128]
    const float* W1 = (const float*)d_in[1];   // [256,16384]
    const float* b1 = (const float*)d_in[2];   // [256]
    const float* W2 = (const float*)d_in[3];   // [11,256]
    const float* b2 = (const float*)d_in[4];   // [11]
    float* out = (float*)d_out;                // [50,128,11]

    float* part = (float*)d_ws;                          // 4 * 6400*256 fp32 = 26.2 MB
    float* cur1 = part + (size_t)KSPLIT * M_TOT * NH;    // 6.55 MB
    float* spk1 = cur1 + (size_t)M_TOT * NH;             // 6.55 MB
    float* cur2 = spk1 + (size_t)M_TOT * NH;             // 6400*16 fp32 = 0.41 MB

    dim3 g1(M_TOT / BM, NH / BN, KSPLIT);                // (100,4,4)
    gemm1_kernel<<<g1, 256, 0, stream>>>(x, W1, part);
    reduce_kernel<<<(M_TOT * NH / 4) / 256, 256, 0, stream>>>(part, b1, cur1);
    scan1_kernel<<<BATCH, NH, 0, stream>>>(cur1, spk1);
    gemm2_kernel<<<M_TOT / 4, 256, 0, stream>>>(spk1, W2, b2, cur2);
    scan2_kernel<<<(BATCH * NO + 255) / 256, 256, 0, stream>>>(cur2, out);
}

// Round 2
// 666.586 us; speedup vs baseline: 2.0920x; 2.0920x over previous
//
#include <hip/hip_runtime.h>

// SmallSNN: T=50, B=128, ni=16384, nh=256, no=11
// Pipeline: gemm1_mfma (f16x2-limb split-fp32 MFMA, fused conversion, split-K=8)
//        -> scan1 (split-K reduce + bias + membrane recursion -> spk1)
//        -> gemm2 (spk1 @ W2.T + b2, wave-per-row)
//        -> scan2 (layer-2 membrane recursion -> out)

#define T_STEPS 50
#define BATCH   128
#define NI      16384
#define NH      256
#define NO      11
#define M_TOT   (T_STEPS * BATCH)   // 6400
#define KSPLIT  8
#define KCHUNK  (NI / KSPLIT)       // 2048
#define BK      32
#define KTILES  (KCHUNK / BK)       // 64
#define BM      128
#define BN      256

typedef _Float16 f16x8 __attribute__((ext_vector_type(8)));
typedef float    f32x4 __attribute__((ext_vector_type(4)));

__device__ __forceinline__ void split2(float f, _Float16& hi, _Float16& lo) {
    hi = (_Float16)f;                 // RN
    lo = (_Float16)(f - (float)hi);   // exact residual, then RN -> ~2^-24 total
}

// ---------------------------------------------------------------------------
// gemm1: part[ks][m][n] = sum_{k in chunk ks} X[m][k] * W1[n][k]
// 128x256 block tile, 4 waves of 64x128, 16x16x32 f16 MFMA, 3 limb products.
// ---------------------------------------------------------------------------
__global__ __launch_bounds__(256, 2) void gemm1_mfma(
    const float* __restrict__ X, const float* __restrict__ W1,
    float* __restrict__ part)
{
    __shared__ alignas(16) _Float16 Ah[BM * BK];   // 8 KB
    __shared__ alignas(16) _Float16 Al[BM * BK];   // 8 KB
    __shared__ alignas(16) _Float16 Bh[BN * BK];   // 16 KB
    __shared__ alignas(16) _Float16 Bl[BN * BK];   // 16 KB

    const int tid  = threadIdx.x;
    const int lane = tid & 63;
    const int wave = tid >> 6;
    const int wm   = wave >> 1;       // 0..1 : m offset 64*wm
    const int wn   = wave & 1;        // 0..1 : n offset 128*wn
    const int q    = lane >> 4;       // quad 0..3
    const int l15  = lane & 15;

    const int m0 = blockIdx.x * BM;   // 0..6272
    const int ks = blockIdx.y;        // 0..7
    const int kbase = ks * KCHUNK;

    // staging assignments (groups of 8 consecutive k)
    const int a_row[2] = { (tid + 0) >> 2, (tid + 256) >> 2 };
    const int a_g8 [2] = { (tid + 0) & 3,  (tid + 256) & 3 };
    int b_row[4], b_g8[4];
#pragma unroll
    for (int i = 0; i < 4; ++i) { b_row[i] = (tid + 256 * i) >> 2; b_g8[i] = (tid + 256 * i) & 3; }

    f32x4 acc[4][8];
#pragma unroll
    for (int im = 0; im < 4; ++im)
#pragma unroll
        for (int jn = 0; jn < 8; ++jn) acc[im][jn] = (f32x4){0.f, 0.f, 0.f, 0.f};

    for (int kt = 0; kt < KTILES; ++kt) {
        const int k0 = kbase + kt * BK;

        // ---- global loads (fp32) ----
        float av[2][8], bv[4][8];
#pragma unroll
        for (int i = 0; i < 2; ++i) {
            const float* s = X + (size_t)(m0 + a_row[i]) * NI + k0 + a_g8[i] * 8;
            float4 v0 = *(const float4*)s, v1 = *(const float4*)(s + 4);
            av[i][0]=v0.x; av[i][1]=v0.y; av[i][2]=v0.z; av[i][3]=v0.w;
            av[i][4]=v1.x; av[i][5]=v1.y; av[i][6]=v1.z; av[i][7]=v1.w;
        }
#pragma unroll
        for (int i = 0; i < 4; ++i) {
            const float* s = W1 + (size_t)b_row[i] * NI + k0 + b_g8[i] * 8;
            float4 v0 = *(const float4*)s, v1 = *(const float4*)(s + 4);
            bv[i][0]=v0.x; bv[i][1]=v0.y; bv[i][2]=v0.z; bv[i][3]=v0.w;
            bv[i][4]=v1.x; bv[i][5]=v1.y; bv[i][6]=v1.z; bv[i][7]=v1.w;
        }

        // ---- convert to limb pairs (VALU only, pre-barrier) ----
        f16x8 ahv[2], alv[2], bhv[4], blv[4];
#pragma unroll
        for (int i = 0; i < 2; ++i)
#pragma unroll
            for (int j = 0; j < 8; ++j) { _Float16 h, l; split2(av[i][j], h, l); ahv[i][j] = h; alv[i][j] = l; }
#pragma unroll
        for (int i = 0; i < 4; ++i)
#pragma unroll
            for (int j = 0; j < 8; ++j) { _Float16 h, l; split2(bv[i][j], h, l); bhv[i][j] = h; blv[i][j] = l; }

        __syncthreads();   // all waves done reading previous tile

#pragma unroll
        for (int i = 0; i < 2; ++i) {
            const int off = a_row[i] * BK + a_g8[i] * 8;
            *(f16x8*)&Ah[off] = ahv[i];
            *(f16x8*)&Al[off] = alv[i];
        }
#pragma unroll
        for (int i = 0; i < 4; ++i) {
            const int off = b_row[i] * BK + b_g8[i] * 8;
            *(f16x8*)&Bh[off] = bhv[i];
            *(f16x8*)&Bl[off] = blv[i];
        }

        __syncthreads();   // staging visible

        // ---- fragments + MFMA ----
        // A[m = l15][k = q*8+j], B^T[n = l15][k = q*8+j]; D: row=q*4+r, col=l15
        f16x8 fah[4], fal[4], fbh[8], fbl[8];
#pragma unroll
        for (int im = 0; im < 4; ++im) {
            const int off = (64 * wm + 16 * im + l15) * BK + q * 8;
            fah[im] = *(const f16x8*)&Ah[off];
            fal[im] = *(const f16x8*)&Al[off];
        }
#pragma unroll
        for (int jn = 0; jn < 8; ++jn) {
            const int off = (128 * wn + 16 * jn + l15) * BK + q * 8;
            fbh[jn] = *(const f16x8*)&Bh[off];
            fbl[jn] = *(const f16x8*)&Bl[off];
        }
#pragma unroll
        for (int im = 0; im < 4; ++im)
#pragma unroll
            for (int jn = 0; jn < 8; ++jn) {
                acc[im][jn] = __builtin_amdgcn_mfma_f32_16x16x32_f16(fah[im], fbh[jn], acc[im][jn], 0, 0, 0);
                acc[im][jn] = __builtin_amdgcn_mfma_f32_16x16x32_f16(fal[im], fbh[jn], acc[im][jn], 0, 0, 0);
                acc[im][jn] = __builtin_amdgcn_mfma_f32_16x16x32_f16(fah[im], fbl[jn], acc[im][jn], 0, 0, 0);
            }
    }

    // ---- epilogue: write fp32 partials ----
    float* P = part + (size_t)ks * M_TOT * NH;
#pragma unroll
    for (int im = 0; im < 4; ++im) {
        const int mrow = m0 + 64 * wm + 16 * im + 4 * q;
#pragma unroll
        for (int jn = 0; jn < 8; ++jn) {
            const int n = 128 * wn + 16 * jn + l15;
#pragma unroll
            for (int r = 0; r < 4; ++r)
                P[(size_t)(mrow + r) * NH + n] = acc[im][jn][r];
        }
    }
}

// split-K reduce + bias + layer-1 membrane recursion; emits spk1
__global__ __launch_bounds__(256) void scan1_kernel(
    const float* __restrict__ part, const float* __restrict__ b1,
    float* __restrict__ spk1)
{
    const int b = blockIdx.x;    // 0..127
    const int h = threadIdx.x;   // 0..255
    const float bias = b1[h];
    const size_t S = (size_t)M_TOT * NH;
    float mem = 0.f;
    for (int t = 0; t < T_STEPS; ++t) {
        const size_t idx = ((size_t)(t * BATCH + b)) * NH + h;
        float c = ((part[idx] + part[S + idx]) + (part[2 * S + idx] + part[3 * S + idx]))
                + ((part[4 * S + idx] + part[5 * S + idx]) + (part[6 * S + idx] + part[7 * S + idx]));
        c += bias;
        mem = __fadd_rn(__fmul_rn(0.9f, mem), c);
        const float s = (mem > 1.0f) ? 1.0f : 0.0f;
        mem -= s;
        spk1[idx] = s;
    }
}

// cur2 = spk1 @ W2.T + b2 ; wave-per-row, shfl-xor tree reduction (K=256)
__global__ __launch_bounds__(256) void gemm2_kernel(
    const float* __restrict__ spk1, const float* __restrict__ W2,
    const float* __restrict__ b2, float* __restrict__ cur2)
{
    const int wave = threadIdx.x >> 6;
    const int lane = threadIdx.x & 63;
    const int m = blockIdx.x * 4 + wave;   // 0..6399
    const float4 s4 = *(const float4*)(spk1 + (size_t)m * NH + (lane << 2));
#pragma unroll
    for (int o = 0; o < NO; ++o) {
        const float4 w4 = *(const float4*)(W2 + (size_t)o * NH + (lane << 2));
        float p = (s4.x * w4.x + s4.y * w4.y) + (s4.z * w4.z + s4.w * w4.w);
#pragma unroll
        for (int d = 32; d; d >>= 1) p += __shfl_xor(p, d, 64);
        if (lane == 0) cur2[(size_t)m * 16 + o] = p + b2[o];
    }
}

// layer-2 membrane recursion; emits spk2 = final output
__global__ __launch_bounds__(256) void scan2_kernel(
    const float* __restrict__ cur2, float* __restrict__ out)
{
    const int tid = blockIdx.x * 256 + threadIdx.x;
    if (tid >= BATCH * NO) return;
    const int b = tid / NO, o = tid % NO;
    float mem = 0.f;
    for (int t = 0; t < T_STEPS; ++t) {
        const float c = cur2[(size_t)(t * BATCH + b) * 16 + o];
        mem = __fadd_rn(__fmul_rn(0.9f, mem), c);
        const float s = (mem > 1.0f) ? 1.0f : 0.0f;
        mem -= s;
        out[(size_t)(t * BATCH + b) * NO + o] = s;
    }
}

extern "C" void kernel_launch(void* const* d_in, const int* in_sizes, int n_in,
                              void* d_out, int out_size, void* d_ws, size_t ws_size,
                              hipStream_t stream) {
    const float* x  = (const float*)d_in[0];   // [50,128,128,128]
    const float* W1 = (const float*)d_in[1];   // [256,16384]
    const float* b1 = (const float*)d_in[2];   // [256]
    const float* W2 = (const float*)d_in[3];   // [11,256]
    const float* b2 = (const float*)d_in[4];   // [11]
    float* out = (float*)d_out;                // [50,128,11]

    float* part = (float*)d_ws;                          // 8 * 6400*256 fp32 = 52.4 MB
    float* spk1 = part + (size_t)KSPLIT * M_TOT * NH;    // 6.55 MB
    float* cur2 = spk1 + (size_t)M_TOT * NH;             // 6400*16 fp32 = 0.41 MB

    dim3 g1(M_TOT / BM, KSPLIT);                         // (50, 8)
    gemm1_mfma<<<g1, 256, 0, stream>>>(x, W1, part);
    scan1_kernel<<<BATCH, NH, 0, stream>>>(part, b1, spk1);
    gemm2_kernel<<<M_TOT / 4, 256, 0, stream>>>(spk1, W2, b2, cur2);
    scan2_kernel<<<(BATCH * NO + 255) / 256, 256, 0, stream>>>(cur2, out);
}